// Round 1
// baseline (79.461 us; speedup 1.0000x reference)
//
#include <hip/hip_runtime.h>
#include <math.h>

#define SIZE 128
#define BATCH 64
#define STEEP 10.0f
#define INV_PI 0.3183098861837907f

// One block = one (batch, row-chunk of 32). 4 waves/block, each wave owns 8 rows.
// Lane p owns columns (2p, 2p+1) of X for its 8 rows, plus x[2p], x[2p+1]
// (x redundant per wave). Even layers are lane-local; odd layers exchange with
// neighbor lanes via __shfl. No LDS, no barriers.
__global__ __launch_bounds__(256) void soft_sort_kernel(
    const float* __restrict__ vec, float* __restrict__ out)
{
    const int tid      = threadIdx.x;
    const int lane     = tid & 63;
    const int wave     = tid >> 6;
    const int batch    = blockIdx.x >> 2;
    const int rowchunk = blockIdx.x & 3;
    const int r_base   = rowchunk * 32 + wave * 8;

    const int c0 = 2 * lane;
    const int c1 = c0 + 1;

    // Load this lane's two x values (coalesced float2).
    const float2 xv = *reinterpret_cast<const float2*>(vec + batch * SIZE + c0);
    float xa = xv.x, xb = xv.y;

    // X = identity
    float XA[8], XB[8];
#pragma unroll
    for (int i = 0; i < 8; ++i) {
        const int row = r_base + i;
        XA[i] = (row == c0) ? 1.0f : 0.0f;
        XB[i] = (row == c1) ? 1.0f : 0.0f;
    }

    // Clamped neighbor lanes (edge lanes get finite garbage, predicated out).
    const int laneR = (lane < 63) ? lane + 1 : 63;
    const int laneL = (lane > 0)  ? lane - 1 : 0;
    const bool hasR = (lane < 63);
    const bool hasL = (lane > 0);

    for (int layer = 0; layer < SIZE; layer += 2) {
        // ---- even layer: pair (2p, 2p+1), fully lane-local ----
        {
            const float alpha = atanf(STEEP * (xb - xa)) * INV_PI + 0.5f;
            // a' = alpha*a + (1-alpha)*b = b + alpha*(a-b)
            // b' = (1-alpha)*a + alpha*b = a - alpha*(a-b)
            const float t  = alpha * (xa - xb);
            const float na = xb + t;
            xb = xa - t;
            xa = na;
#pragma unroll
            for (int i = 0; i < 8; ++i) {
                const float tr = alpha * (XA[i] - XB[i]);
                const float nA = XB[i] + tr;
                XB[i] = XA[i] - tr;
                XA[i] = nA;
            }
        }
        // ---- odd layer: pair (2p+1, 2p+2) spans lanes p and p+1 ----
        {
            const float xnext  = __shfl(xa, laneR);            // old x[2p+2]
            const float alphaR = atanf(STEEP * (xnext - xb)) * INV_PI + 0.5f;
            const float alphaL = __shfl(alphaR, laneL);        // alpha of pair (2p-1,2p)
            const float xprev  = __shfl(xb, laneL);            // old x[2p-1]

            // xb is "a" of pair p:   a' = b + w*(a-b),  b = xnext, w = alphaR
            // xa is "b" of pair p-1: b' = a + w*(b-a),  a = xprev, w = alphaL
            const float nxb = xnext + alphaR * (xb - xnext);
            const float nxa = xprev + alphaL * (xa - xprev);
            xb = hasR ? nxb : xb;
            xa = hasL ? nxa : xa;
#pragma unroll
            for (int i = 0; i < 8; ++i) {
                const float nA = __shfl(XA[i], laneR);   // old col 2p+2
                const float pB = __shfl(XB[i], laneL);   // old col 2p-1
                const float nXB = nA + alphaR * (XB[i] - nA);
                const float nXA = pB + alphaL * (XA[i] - pB);
                XB[i] = hasR ? nXB : XB[i];
                XA[i] = hasL ? nXA : XA[i];
            }
        }
    }

    // ---- store ----
    // Layout: out[0 .. 8191] = x (64x128); out[8192 ..] = X (64x128x128) row-major.
    float* __restrict__ Xout = out + BATCH * SIZE + batch * SIZE * SIZE;
#pragma unroll
    for (int i = 0; i < 8; ++i) {
        const int row = r_base + i;
        *reinterpret_cast<float2*>(Xout + row * SIZE + c0) = make_float2(XA[i], XB[i]);
    }
    if (rowchunk == 0 && wave == 0) {
        *reinterpret_cast<float2*>(out + batch * SIZE + c0) = make_float2(xa, xb);
    }
}

extern "C" void kernel_launch(void* const* d_in, const int* in_sizes, int n_in,
                              void* d_out, int out_size, void* d_ws, size_t ws_size,
                              hipStream_t stream) {
    const float* vec = (const float*)d_in[0];
    float* out = (float*)d_out;
    (void)in_sizes; (void)n_in; (void)d_ws; (void)ws_size; (void)out_size;

    dim3 grid(BATCH * 4);   // 64 batches x 4 row-chunks
    dim3 block(256);
    hipLaunchKernelGGL(soft_sort_kernel, grid, block, 0, stream, vec, out);
}